// Round 6
// baseline (370.463 us; speedup 1.0000x reference)
//
#include <hip/hip_runtime.h>
#include <math.h>

#define DD 512
#define MM 512
#define BB 32
#define TT 4
#define VV 32000

// ---- fused gather + (softmax-weighted) partial sum.  [round-4 verified]
// block = b*32 + c; handles m in [c*16, c*16+16) -> 64 story rows.
// partial[(b*32+c)][d] = sum_{m in chunk} w[b][m] * sum_t table[story[b,m,t]][d]
// w = softmax(s[b]) computed redundantly per block; s==null -> 1/M (mean pool).
__global__ __launch_bounds__(256) void poolwsum_kernel(const float* __restrict__ table,
                                                       const int* __restrict__ story,
                                                       const float* __restrict__ s,
                                                       float* __restrict__ partial) {
  __shared__ float wsh[16];
  __shared__ int rows[64];
  __shared__ float red[16];
  int b = blockIdx.x >> 5;
  int c = blockIdx.x & 31;
  int t = threadIdx.x;
  if (s) {
    float v0 = s[b * MM + t], v1 = s[b * MM + t + 256];
    float mx = fmaxf(v0, v1);
#pragma unroll
    for (int off = 32; off > 0; off >>= 1) mx = fmaxf(mx, __shfl_xor(mx, off));
    if ((t & 63) == 0) red[t >> 6] = mx;
    __syncthreads();
    mx = fmaxf(fmaxf(red[0], red[1]), fmaxf(red[2], red[3]));
    float e0 = expf(v0 - mx), e1 = expf(v1 - mx);
    float sm = e0 + e1;
#pragma unroll
    for (int off = 32; off > 0; off >>= 1) sm += __shfl_xor(sm, off);
    if ((t & 63) == 0) red[8 + (t >> 6)] = sm;
    __syncthreads();
    sm = red[8] + red[9] + red[10] + red[11];
    float inv = 1.0f / sm;
    if (t < 16) wsh[t] = expf(s[b * MM + c * 16 + t] - mx) * inv;
  } else {
    if (t < 16) wsh[t] = 1.0f / MM;
  }
  if (t < 64) rows[t] = story[((b << 9) + (c << 4)) * TT + t];
  __syncthreads();
  float acc0 = 0.f, acc1 = 0.f;
#pragma unroll 8
  for (int i = 0; i < 64; ++i) {
    const float* r = table + (size_t)rows[i] * DD;
    float wm = wsh[i >> 2];
    acc0 += wm * r[t];
    acc1 += wm * r[t + 256];
  }
  float* pp = partial + (size_t)blockIdx.x * DD;
  pp[t] = acc0;
  pp[t + 256] = acc1;
}

// ---- stage B: uout[b][d] = (prev ? prev[b][d] : 0) + sum_{c<32} partial[b*32+c][d]
__global__ void wsumB_kernel(const float* __restrict__ partial,
                             const float* __restrict__ prev,
                             float* __restrict__ uout) {
  int i = blockIdx.x * 256 + threadIdx.x;   // 64 blocks -> B*D
  int b = i >> 9, d = i & 511;
  float acc = prev ? prev[i] : 0.f;
  const float* pp = partial + (size_t)b * 32 * DD + d;
#pragma unroll
  for (int c = 0; c < 32; ++c) acc += pp[c * DD];
  uout[i] = acc;
}

// ---- stage B, decoder hop0: o0 = sum partials; uk = hid + o0; hc = [hid | o0]
__global__ void wsumB2_kernel(const float* __restrict__ partial,
                              const float* __restrict__ hid,
                              float* __restrict__ uk, float* __restrict__ hc) {
  int i = blockIdx.x * 256 + threadIdx.x;
  int b = i >> 9, d = i & 511;
  float ov = 0.f;
  const float* pp = partial + (size_t)b * 32 * DD + d;
#pragma unroll
  for (int c = 0; c < 32; ++c) ov += pp[c * DD];
  float hv = hid[i];
  uk[i] = hv + ov;
  hc[b * 1024 + d] = hv;
  hc[b * 1024 + 512 + d] = ov;
}

// ---- dense dot: dotv[b][v] = C[v][:] . u[b][:].  GEMM [32000x512]x[512x32].
// 500 blocks, tile 64v x 32b, thread 4b x 2v, K-chunk 32, reg double-buffer.
__global__ __launch_bounds__(256) void dotV_kernel(const float* __restrict__ u,
                                                   const float* __restrict__ C,
                                                   float* __restrict__ dotv) {
  __shared__ float As[32][36];
  __shared__ float Bs[32][68];
  int t = threadIdx.x;
  int v0 = blockIdx.x * 64;
  int tb = t >> 5;
  int tv = t & 31;
  int br = t >> 2;
  int bk = (t & 3) << 3;
  const float* Wp = C + (size_t)(v0 + br) * DD + bk;
  int ab = t >> 3;
  int ak = (t & 7) << 2;
  const float* Ap = u + (size_t)ab * DD + ak;

  float acc[4][2] = {{0.f, 0.f}, {0.f, 0.f}, {0.f, 0.f}, {0.f, 0.f}};

  float4 aReg = *(const float4*)(Ap);
  float4 wReg0 = *(const float4*)(Wp);
  float4 wReg1 = *(const float4*)(Wp + 4);

  for (int k0 = 0; k0 < DD; k0 += 32) {
    As[ak + 0][ab] = aReg.x; As[ak + 1][ab] = aReg.y;
    As[ak + 2][ab] = aReg.z; As[ak + 3][ab] = aReg.w;
    Bs[bk + 0][br] = wReg0.x; Bs[bk + 1][br] = wReg0.y;
    Bs[bk + 2][br] = wReg0.z; Bs[bk + 3][br] = wReg0.w;
    Bs[bk + 4][br] = wReg1.x; Bs[bk + 5][br] = wReg1.y;
    Bs[bk + 6][br] = wReg1.z; Bs[bk + 7][br] = wReg1.w;
    __syncthreads();
    if (k0 + 32 < DD) {
      aReg = *(const float4*)(Ap + k0 + 32);
      wReg0 = *(const float4*)(Wp + k0 + 32);
      wReg1 = *(const float4*)(Wp + k0 + 36);
    }
#pragma unroll
    for (int k = 0; k < 32; ++k) {
      float2 bv = *(const float2*)&Bs[k][tv * 2];
      float4 av = *(const float4*)&As[k][tb * 4];
      acc[0][0] += av.x * bv.x; acc[0][1] += av.x * bv.y;
      acc[1][0] += av.y * bv.x; acc[1][1] += av.y * bv.y;
      acc[2][0] += av.z * bv.x; acc[2][1] += av.z * bv.y;
      acc[3][0] += av.w * bv.x; acc[3][1] += av.w * bv.y;
    }
    __syncthreads();
  }
  int v = v0 + tv * 2;
#pragma unroll
  for (int i = 0; i < 4; ++i) {
    float2 r;
    r.x = acc[i][0];
    r.y = acc[i][1];
    *(float2*)(dotv + (size_t)(tb * 4 + i) * VV + v) = r;
  }
}

// ---- s[b][m] = sum_t dotv[b][story[b,m,t]]  (logits; also used for p_ptr)
__global__ void gatherS_kernel(const float* __restrict__ dotv,
                               const int* __restrict__ story,
                               float* __restrict__ out) {
  int i = blockIdx.x * 256 + threadIdx.x;   // 64 blocks -> B*M
  int b = i >> 9;
  const float* dv = dotv + (size_t)b * VV;
  int4 ix = *(const int4*)(story + (size_t)i * 4);
  out[i] = dv[ix.x] + dv[ix.y] + dv[ix.z] + dv[ix.w];
}

// ---- out[b][j] = bias[j] + W[j] . (vin ? vin[b] : table[q[b]]). One wave per (b,j).
__global__ __launch_bounds__(256) void matvec_kernel(const float* __restrict__ W,
                                                     const float* __restrict__ bias,
                                                     const float* __restrict__ vin,
                                                     const int* __restrict__ q,
                                                     const float* __restrict__ table,
                                                     float* __restrict__ out) {
  int idx = (blockIdx.x << 2) + (threadIdx.x >> 6);  // b*1536 + j
  int lane = threadIdx.x & 63;
  int b = idx / 1536;
  int j = idx - b * 1536;
  const float* xb = vin ? (vin + (size_t)b * DD) : (table + (size_t)q[b] * DD);
  const float4* Wr = (const float4*)(W + (size_t)j * DD);
  const float4* xr = (const float4*)xb;
  float acc = 0.f;
#pragma unroll
  for (int h = 0; h < 2; ++h) {
    int c = (h << 6) + lane;
    float4 a = Wr[c];
    float4 qv = xr[c];
    acc += a.x * qv.x + a.y * qv.y + a.z * qv.z + a.w * qv.w;
  }
#pragma unroll
  for (int off = 32; off > 0; off >>= 1) acc += __shfl_xor(acc, off);
  if (lane == 0) out[idx] = acc + bias[j];
}

// ---- GRU gates: hidden = (1-z)*n + z*u
__global__ void gate_kernel(const float* __restrict__ gi, const float* __restrict__ gh,
                            const float* __restrict__ u, float* __restrict__ hidden,
                            float* __restrict__ out_h) {
  int i = blockIdx.x * 256 + threadIdx.x;  // B*D
  int b = i >> 9, d = i & 511;
  const float* gib = gi + b * 1536;
  const float* ghb = gh + b * 1536;
  float i_r = gib[d], i_z = gib[d + 512], i_n = gib[d + 1024];
  float h_r = ghb[d], h_z = ghb[d + 512], h_n = ghb[d + 1024];
  float r = 1.f / (1.f + expf(-(i_r + h_r)));
  float z = 1.f / (1.f + expf(-(i_z + h_z)));
  float n = tanhf(i_n + r * h_n);
  float h = (1.f - z) * n + z * u[i];
  hidden[i] = h;
  out_h[i] = h;
}

// ---- p_vocab[b][v] = Hcat[b][:] . W1[v][:] + W1b[v].  [32 x 32000], K = 1024.
__global__ __launch_bounds__(256) void pvocab_kernel(const float* __restrict__ Hcat,
                                                     const float* __restrict__ W1,
                                                     const float* __restrict__ W1b,
                                                     float* __restrict__ out) {
  __shared__ float As[32][36];
  __shared__ float Bs[32][68];
  int t = threadIdx.x;
  int v0 = blockIdx.x * 64;
  int tb = t >> 5;
  int tv = t & 31;
  int br = t >> 2;
  int bk = (t & 3) << 3;
  const float* Wp = W1 + (size_t)(v0 + br) * 1024 + bk;
  int ab = t >> 3;
  int ak = (t & 7) << 2;
  const float* Ap = Hcat + (size_t)ab * 1024 + ak;

  float acc[4][2] = {{0.f, 0.f}, {0.f, 0.f}, {0.f, 0.f}, {0.f, 0.f}};

  float4 aReg = *(const float4*)(Ap);
  float4 wReg0 = *(const float4*)(Wp);
  float4 wReg1 = *(const float4*)(Wp + 4);

  for (int k0 = 0; k0 < 1024; k0 += 32) {
    As[ak + 0][ab] = aReg.x; As[ak + 1][ab] = aReg.y;
    As[ak + 2][ab] = aReg.z; As[ak + 3][ab] = aReg.w;
    Bs[bk + 0][br] = wReg0.x; Bs[bk + 1][br] = wReg0.y;
    Bs[bk + 2][br] = wReg0.z; Bs[bk + 3][br] = wReg0.w;
    Bs[bk + 4][br] = wReg1.x; Bs[bk + 5][br] = wReg1.y;
    Bs[bk + 6][br] = wReg1.z; Bs[bk + 7][br] = wReg1.w;
    __syncthreads();
    if (k0 + 32 < 1024) {
      aReg = *(const float4*)(Ap + k0 + 32);
      wReg0 = *(const float4*)(Wp + k0 + 32);
      wReg1 = *(const float4*)(Wp + k0 + 36);
    }
#pragma unroll
    for (int k = 0; k < 32; ++k) {
      float2 bv = *(const float2*)&Bs[k][tv * 2];
      float4 av = *(const float4*)&As[k][tb * 4];
      acc[0][0] += av.x * bv.x; acc[0][1] += av.x * bv.y;
      acc[1][0] += av.y * bv.x; acc[1][1] += av.y * bv.y;
      acc[2][0] += av.z * bv.x; acc[2][1] += av.z * bv.y;
      acc[3][0] += av.w * bv.x; acc[3][1] += av.w * bv.y;
    }
    __syncthreads();
  }
  int v = v0 + tv * 2;
  float b0 = W1b[v], b1 = W1b[v + 1];
#pragma unroll
  for (int i = 0; i < 4; ++i) {
    float2 r;
    r.x = acc[i][0] + b0;
    r.y = acc[i][1] + b1;
    *(float2*)(out + (size_t)(tb * 4 + i) * VV + v) = r;
  }
}

extern "C" void kernel_launch(void* const* d_in, const int* in_sizes, int n_in,
                              void* d_out, int out_size, void* d_ws, size_t ws_size,
                              hipStream_t stream) {
  const int* story = (const int*)d_in[0];
  const int* q = (const int*)d_in[1];
  const float* C_enc = (const float*)d_in[2];
  const float* C_dec = (const float*)d_in[3];
  const float* W_ih = (const float*)d_in[4];
  const float* W_hh = (const float*)d_in[5];
  const float* b_ih = (const float*)d_in[6];
  const float* b_hh = (const float*)d_in[7];
  const float* W1 = (const float*)d_in[8];
  const float* W1b = (const float*)d_in[9];
  float* out = (float*)d_out;

  const size_t VD = (size_t)VV * DD;
  const float* C1 = C_enc + 1 * VD;
  const float* C2 = C_enc + 2 * VD;
  const float* C3 = C_enc + 3 * VD;
  const float* D0 = C_dec + 0 * VD;
  const float* D1 = C_dec + 1 * VD;
  const float* D2 = C_dec + 2 * VD;

  float* part = (float*)d_ws;              // [B*32*D]
  float* dotv = part + (size_t)BB * 32 * DD;   // [B*V]
  float* u = dotv + (size_t)BB * VV;       // [B*D]
  float* s = u + BB * DD;                  // [B*M]
  float* gi = s + BB * MM;                 // [B*3D]
  float* gh = gi + BB * 3 * DD;            // [B*3D]
  float* hid = gh + BB * 3 * DD;           // [B*D]
  float* uk = hid + BB * DD;               // [B*D]
  float* hc = uk + BB * DD;                // [B*2D]

  float* p_ptr_out = out;
  float* p_vocab_out = out + BB * MM;
  float* hid_out = out + BB * MM + (size_t)BB * VV;

  dim3 blk(256);
  const int pwGrid = BB * 32;         // 1024 blocks (64 rows each)
  const int mvGrid = BB * 3 * DD / 4; // 3072 blocks
  const int ewGrid = BB * DD / 256;   // 64

  // ---------------- encoder (u0 = 0 => hop0 softmax uniform; C_enc[0] unused)
  poolwsum_kernel<<<pwGrid, blk, 0, stream>>>(C1, story, nullptr, part);
  wsumB_kernel<<<ewGrid, blk, 0, stream>>>(part, nullptr, u);      // u1 = mean pool
  dotV_kernel<<<VV / 64, blk, 0, stream>>>(u, C1, dotv);           // C1 . u1 (C1 L3-hot)
  gatherS_kernel<<<ewGrid, blk, 0, stream>>>(dotv, story, s);      // s1
  poolwsum_kernel<<<pwGrid, blk, 0, stream>>>(C2, story, s, part); // softmax folded
  wsumB_kernel<<<ewGrid, blk, 0, stream>>>(part, u, u);            // u2
  dotV_kernel<<<VV / 64, blk, 0, stream>>>(u, C2, dotv);           // C2 . u2 (C2 L3-hot)
  gatherS_kernel<<<ewGrid, blk, 0, stream>>>(dotv, story, s);      // s2
  poolwsum_kernel<<<pwGrid, blk, 0, stream>>>(C3, story, s, part);
  wsumB_kernel<<<ewGrid, blk, 0, stream>>>(part, u, u);            // u3 = enc_hidden

  // ---------------- GRU step (embed folded into matvec_gi)
  matvec_kernel<<<mvGrid, blk, 0, stream>>>(W_ih, b_ih, nullptr, q, C_dec, gi);
  matvec_kernel<<<mvGrid, blk, 0, stream>>>(W_hh, b_hh, u, nullptr, nullptr, gh);
  gate_kernel<<<ewGrid, blk, 0, stream>>>(gi, gh, u, hid, hid_out);

  // ---------------- pointer decoder (C_dec[3] pooled is dead code)
  dotV_kernel<<<VV / 64, blk, 0, stream>>>(hid, D0, dotv);         // D0 . hid
  gatherS_kernel<<<ewGrid, blk, 0, stream>>>(dotv, story, s);      // hop0 logits
  poolwsum_kernel<<<pwGrid, blk, 0, stream>>>(D1, story, s, part);
  wsumB2_kernel<<<ewGrid, blk, 0, stream>>>(part, hid, uk, hc);    // o0, uk1, hcat
  dotV_kernel<<<VV / 64, blk, 0, stream>>>(uk, D1, dotv);          // D1 . uk1 (D1 hot)
  gatherS_kernel<<<ewGrid, blk, 0, stream>>>(dotv, story, s);      // hop1 logits
  poolwsum_kernel<<<pwGrid, blk, 0, stream>>>(D2, story, s, part);
  wsumB_kernel<<<ewGrid, blk, 0, stream>>>(part, uk, uk);          // uk2
  dotV_kernel<<<VV / 64, blk, 0, stream>>>(uk, D2, dotv);          // D2 . uk2 (D2 hot)
  gatherS_kernel<<<ewGrid, blk, 0, stream>>>(dotv, story, p_ptr_out); // p_ptr

  // ---------------- vocab projection
  pvocab_kernel<<<VV / 64, blk, 0, stream>>>(hc, W1, W1b, p_vocab_out);
}

// Round 7
// 302.657 us; speedup vs baseline: 1.2240x; 1.2240x over previous
//
#include <hip/hip_runtime.h>
#include <math.h>

#define DD 512
#define MM 512
#define BB 32
#define TT 4
#define VV 32000

// ---- fused gather + (softmax-weighted) partial sum, float4 loads.
// block = b*32 + c; handles m in [c*16, c*16+16) -> 64 story rows.
// partial[(b*32+c)][d] = sum_{m in chunk} w[b][m] * sum_t table[story[b,m,t]][d]
// w = softmax(s[b]) computed redundantly per block; s==null -> 1/M (mean pool).
// Threads split in halves: half h accumulates rows i≡h (mod 2) as float4 over
// col = t&127; halves combined through LDS at the end.
__global__ __launch_bounds__(256) void poolwsum_kernel(const float* __restrict__ table,
                                                       const int* __restrict__ story,
                                                       const float* __restrict__ s,
                                                       float* __restrict__ partial) {
  __shared__ float wrow[64];
  __shared__ int rows[64];
  __shared__ float red[16];
  __shared__ float4 comb[128];
  int b = blockIdx.x >> 5;
  int c = blockIdx.x & 31;
  int t = threadIdx.x;
  if (s) {
    float v0 = s[b * MM + t], v1 = s[b * MM + t + 256];
    float mx = fmaxf(v0, v1);
#pragma unroll
    for (int off = 32; off > 0; off >>= 1) mx = fmaxf(mx, __shfl_xor(mx, off));
    if ((t & 63) == 0) red[t >> 6] = mx;
    __syncthreads();
    mx = fmaxf(fmaxf(red[0], red[1]), fmaxf(red[2], red[3]));
    float e0 = expf(v0 - mx), e1 = expf(v1 - mx);
    float sm = e0 + e1;
#pragma unroll
    for (int off = 32; off > 0; off >>= 1) sm += __shfl_xor(sm, off);
    if ((t & 63) == 0) red[8 + (t >> 6)] = sm;
    __syncthreads();
    sm = red[8] + red[9] + red[10] + red[11];
    float inv = 1.0f / sm;
    if (t < 64) {
      rows[t] = story[((b << 9) + (c << 4)) * TT + t];
      wrow[t] = expf(s[b * MM + (c << 4) + (t >> 2)] - mx) * inv;
    }
  } else {
    if (t < 64) {
      rows[t] = story[((b << 9) + (c << 4)) * TT + t];
      wrow[t] = 1.0f / MM;
    }
  }
  __syncthreads();
  int half = t >> 7;          // 0 or 1
  int col = t & 127;          // float4 column
  float4 acc = make_float4(0.f, 0.f, 0.f, 0.f);
  for (int i = half; i < 64; i += 2) {
    float wm = wrow[i];
    float4 v = *((const float4*)(table + (size_t)rows[i] * DD) + col);
    acc.x += wm * v.x; acc.y += wm * v.y;
    acc.z += wm * v.z; acc.w += wm * v.w;
  }
  if (half) comb[col] = acc;
  __syncthreads();
  if (!half) {
    float4 o = comb[col];
    acc.x += o.x; acc.y += o.y; acc.z += o.z; acc.w += o.w;
    ((float4*)(partial + (size_t)blockIdx.x * DD))[col] = acc;
  }
}

// ---- stage B: uout[b][d] = (prev ? prev[b][d] : 0) + sum_{c<32} partial[b*32+c][d]
__global__ void wsumB_kernel(const float* __restrict__ partial,
                             const float* __restrict__ prev,
                             float* __restrict__ uout) {
  int i = blockIdx.x * 256 + threadIdx.x;   // 64 blocks -> B*D
  int b = i >> 9, d = i & 511;
  float acc = prev ? prev[i] : 0.f;
  const float* pp = partial + (size_t)b * 32 * DD + d;
#pragma unroll
  for (int c = 0; c < 32; ++c) acc += pp[c * DD];
  uout[i] = acc;
}

// ---- stage B, decoder hop0: o0 = sum partials; uk = hid + o0; hc = [hid | o0]
__global__ void wsumB2_kernel(const float* __restrict__ partial,
                              const float* __restrict__ hid,
                              float* __restrict__ uk, float* __restrict__ hc) {
  int i = blockIdx.x * 256 + threadIdx.x;
  int b = i >> 9, d = i & 511;
  float ov = 0.f;
  const float* pp = partial + (size_t)b * 32 * DD + d;
#pragma unroll
  for (int c = 0; c < 32; ++c) ov += pp[c * DD];
  float hv = hid[i];
  uk[i] = hv + ov;
  hc[b * 1024 + d] = hv;
  hc[b * 1024 + 512 + d] = ov;
}

// ---- fused gather + dot: s[p] = (sum_t table[story[p,t]]) . u[b]. One wave per p.
__global__ __launch_bounds__(256) void pooldot_kernel(const float* __restrict__ table,
                                                      const int* __restrict__ story,
                                                      const float* __restrict__ u,
                                                      float* __restrict__ s) {
  int wave = (blockIdx.x << 2) + (threadIdx.x >> 6);
  int lane = threadIdx.x & 63;
  int b = wave >> 9;
  const int* st = story + wave * TT;
  size_t r0 = (size_t)st[0] * DD, r1 = (size_t)st[1] * DD;
  size_t r2 = (size_t)st[2] * DD, r3 = (size_t)st[3] * DD;
  const float4* t4 = (const float4*)table;
  const float4* ur = (const float4*)(u + (size_t)b * DD);
  float acc = 0.f;
#pragma unroll
  for (int h = 0; h < 2; ++h) {
    int c = (h << 6) + lane;
    float4 a = t4[(r0 >> 2) + c];
    float4 bb = t4[(r1 >> 2) + c];
    float4 cc = t4[(r2 >> 2) + c];
    float4 d = t4[(r3 >> 2) + c];
    float4 q = ur[c];
    acc += (a.x + bb.x + cc.x + d.x) * q.x;
    acc += (a.y + bb.y + cc.y + d.y) * q.y;
    acc += (a.z + bb.z + cc.z + d.z) * q.z;
    acc += (a.w + bb.w + cc.w + d.w) * q.w;
  }
#pragma unroll
  for (int off = 32; off > 0; off >>= 1) acc += __shfl_xor(acc, off);
  if (lane == 0) s[wave] = acc;
}

// ---- out[b][j] = bias[j] + W[j] . (vin ? vin[b] : table[q[b]]). One wave per (b,j).
__global__ __launch_bounds__(256) void matvec_kernel(const float* __restrict__ W,
                                                     const float* __restrict__ bias,
                                                     const float* __restrict__ vin,
                                                     const int* __restrict__ q,
                                                     const float* __restrict__ table,
                                                     float* __restrict__ out) {
  int idx = (blockIdx.x << 2) + (threadIdx.x >> 6);  // b*1536 + j
  int lane = threadIdx.x & 63;
  int b = idx / 1536;
  int j = idx - b * 1536;
  const float* xb = vin ? (vin + (size_t)b * DD) : (table + (size_t)q[b] * DD);
  const float4* Wr = (const float4*)(W + (size_t)j * DD);
  const float4* xr = (const float4*)xb;
  float acc = 0.f;
#pragma unroll
  for (int h = 0; h < 2; ++h) {
    int c = (h << 6) + lane;
    float4 a = Wr[c];
    float4 qv = xr[c];
    acc += a.x * qv.x + a.y * qv.y + a.z * qv.z + a.w * qv.w;
  }
#pragma unroll
  for (int off = 32; off > 0; off >>= 1) acc += __shfl_xor(acc, off);
  if (lane == 0) out[idx] = acc + bias[j];
}

// ---- GRU gates: hidden = (1-z)*n + z*u
__global__ void gate_kernel(const float* __restrict__ gi, const float* __restrict__ gh,
                            const float* __restrict__ u, float* __restrict__ hidden,
                            float* __restrict__ out_h) {
  int i = blockIdx.x * 256 + threadIdx.x;  // B*D
  int b = i >> 9, d = i & 511;
  const float* gib = gi + b * 1536;
  const float* ghb = gh + b * 1536;
  float i_r = gib[d], i_z = gib[d + 512], i_n = gib[d + 1024];
  float h_r = ghb[d], h_z = ghb[d + 512], h_n = ghb[d + 1024];
  float r = 1.f / (1.f + expf(-(i_r + h_r)));
  float z = 1.f / (1.f + expf(-(i_z + h_z)));
  float n = tanhf(i_n + r * h_n);
  float h = (1.f - z) * n + z * u[i];
  hidden[i] = h;
  out_h[i] = h;
}

// ---- p_vocab partials, split-K x2: partc[kh][b][v] = Hcat[b][kh*512:+512] . W1[v][same]
// grid 1000: vt = blockIdx>>1 (64-v tile), kh = blockIdx&1. No bias here.
__global__ __launch_bounds__(256) void pvocab_kernel(const float* __restrict__ Hcat,
                                                     const float* __restrict__ W1,
                                                     float* __restrict__ partc) {
  __shared__ float As[32][36];
  __shared__ float Bs[32][68];
  int t = threadIdx.x;
  int vt = blockIdx.x >> 1;
  int kh = blockIdx.x & 1;
  int v0 = vt * 64;
  int kbase = kh << 9;            // 0 or 512
  int tb = t >> 5;
  int tv = t & 31;
  int br = t >> 2;
  int bk = (t & 3) << 3;
  const float* Wp = W1 + (size_t)(v0 + br) * 1024 + kbase + bk;
  int ab = t >> 3;
  int ak = (t & 7) << 2;
  const float* Ap = Hcat + (size_t)ab * 1024 + kbase + ak;

  float acc[4][2] = {{0.f, 0.f}, {0.f, 0.f}, {0.f, 0.f}, {0.f, 0.f}};

  float4 aReg = *(const float4*)(Ap);
  float4 wReg0 = *(const float4*)(Wp);
  float4 wReg1 = *(const float4*)(Wp + 4);

  for (int k0 = 0; k0 < 512; k0 += 32) {
    As[ak + 0][ab] = aReg.x; As[ak + 1][ab] = aReg.y;
    As[ak + 2][ab] = aReg.z; As[ak + 3][ab] = aReg.w;
    Bs[bk + 0][br] = wReg0.x; Bs[bk + 1][br] = wReg0.y;
    Bs[bk + 2][br] = wReg0.z; Bs[bk + 3][br] = wReg0.w;
    Bs[bk + 4][br] = wReg1.x; Bs[bk + 5][br] = wReg1.y;
    Bs[bk + 6][br] = wReg1.z; Bs[bk + 7][br] = wReg1.w;
    __syncthreads();
    if (k0 + 32 < 512) {
      aReg = *(const float4*)(Ap + k0 + 32);
      wReg0 = *(const float4*)(Wp + k0 + 32);
      wReg1 = *(const float4*)(Wp + k0 + 36);
    }
#pragma unroll
    for (int k = 0; k < 32; ++k) {
      float2 bv = *(const float2*)&Bs[k][tv * 2];
      float4 av = *(const float4*)&As[k][tb * 4];
      acc[0][0] += av.x * bv.x; acc[0][1] += av.x * bv.y;
      acc[1][0] += av.y * bv.x; acc[1][1] += av.y * bv.y;
      acc[2][0] += av.z * bv.x; acc[2][1] += av.z * bv.y;
      acc[3][0] += av.w * bv.x; acc[3][1] += av.w * bv.y;
    }
    __syncthreads();
  }
  int v = v0 + tv * 2;
  float* base = partc + (size_t)kh * 32 * VV;
#pragma unroll
  for (int i = 0; i < 4; ++i) {
    float2 r;
    r.x = acc[i][0];
    r.y = acc[i][1];
    *(float2*)(base + (size_t)(tb * 4 + i) * VV + v) = r;
  }
}

// ---- out[b][v] = partc[0][b][v] + partc[1][b][v] + W1b[v].  grid (125, 32).
__global__ void pvreduce_kernel(const float* __restrict__ partc,
                                const float* __restrict__ W1b,
                                float* __restrict__ out) {
  int v = blockIdx.x * 256 + threadIdx.x;   // 125*256 = 32000
  int b = blockIdx.y;
  size_t o = (size_t)b * VV + v;
  out[o] = partc[o] + partc[(size_t)32 * VV + o] + W1b[v];
}

extern "C" void kernel_launch(void* const* d_in, const int* in_sizes, int n_in,
                              void* d_out, int out_size, void* d_ws, size_t ws_size,
                              hipStream_t stream) {
  const int* story = (const int*)d_in[0];
  const int* q = (const int*)d_in[1];
  const float* C_enc = (const float*)d_in[2];
  const float* C_dec = (const float*)d_in[3];
  const float* W_ih = (const float*)d_in[4];
  const float* W_hh = (const float*)d_in[5];
  const float* b_ih = (const float*)d_in[6];
  const float* b_hh = (const float*)d_in[7];
  const float* W1 = (const float*)d_in[8];
  const float* W1b = (const float*)d_in[9];
  float* out = (float*)d_out;

  const size_t VD = (size_t)VV * DD;
  const float* C1 = C_enc + 1 * VD;
  const float* C2 = C_enc + 2 * VD;
  const float* C3 = C_enc + 3 * VD;
  const float* D0 = C_dec + 0 * VD;
  const float* D1 = C_dec + 1 * VD;
  const float* D2 = C_dec + 2 * VD;

  float* part = (float*)d_ws;                      // [B*32*D]
  float* partc = part + (size_t)BB * 32 * DD;      // [2*B*V]
  float* u = partc + (size_t)2 * BB * VV;          // [B*D]
  float* s = u + BB * DD;                          // [B*M]
  float* gi = s + BB * MM;                         // [B*3D]
  float* gh = gi + BB * 3 * DD;                    // [B*3D]
  float* hid = gh + BB * 3 * DD;                   // [B*D]
  float* uk = hid + BB * DD;                       // [B*D]
  float* hc = uk + BB * DD;                        // [B*2D]

  float* p_ptr_out = out;
  float* p_vocab_out = out + BB * MM;
  float* hid_out = out + BB * MM + (size_t)BB * VV;

  dim3 blk(256);
  const int pwGrid = BB * 32;         // 1024 blocks (64 rows each)
  const int pdGrid = BB * MM / 4;     // 4096 blocks x 4 waves
  const int mvGrid = BB * 3 * DD / 4; // 3072 blocks
  const int ewGrid = BB * DD / 256;   // 64

  // ---------------- encoder (u0 = 0 => hop0 softmax uniform; C_enc[0] unused)
  // Each table's two gather passes are adjacent -> second pass is L3-hot.
  poolwsum_kernel<<<pwGrid, blk, 0, stream>>>(C1, story, nullptr, part);
  wsumB_kernel<<<ewGrid, blk, 0, stream>>>(part, nullptr, u);      // u1 = mean pool
  pooldot_kernel<<<pdGrid, blk, 0, stream>>>(C1, story, u, s);     // s1 (C1 L3-hot)
  poolwsum_kernel<<<pwGrid, blk, 0, stream>>>(C2, story, s, part); // softmax folded
  wsumB_kernel<<<ewGrid, blk, 0, stream>>>(part, u, u);            // u2
  pooldot_kernel<<<pdGrid, blk, 0, stream>>>(C2, story, u, s);     // s2 (C2 L3-hot)
  poolwsum_kernel<<<pwGrid, blk, 0, stream>>>(C3, story, s, part);
  wsumB_kernel<<<ewGrid, blk, 0, stream>>>(part, u, u);            // u3 = enc_hidden

  // ---------------- GRU step (embed folded into matvec_gi)
  matvec_kernel<<<mvGrid, blk, 0, stream>>>(W_ih, b_ih, nullptr, q, C_dec, gi);
  matvec_kernel<<<mvGrid, blk, 0, stream>>>(W_hh, b_hh, u, nullptr, nullptr, gh);
  gate_kernel<<<ewGrid, blk, 0, stream>>>(gi, gh, u, hid, hid_out);

  // ---------------- pointer decoder (C_dec[3] pooled is dead code)
  pooldot_kernel<<<pdGrid, blk, 0, stream>>>(D0, story, hid, s);   // hop0 logits
  poolwsum_kernel<<<pwGrid, blk, 0, stream>>>(D1, story, s, part);
  wsumB2_kernel<<<ewGrid, blk, 0, stream>>>(part, hid, uk, hc);    // o0, uk1, hcat
  pooldot_kernel<<<pdGrid, blk, 0, stream>>>(D1, story, uk, s);    // hop1 logits (D1 hot)
  poolwsum_kernel<<<pwGrid, blk, 0, stream>>>(D2, story, s, part);
  wsumB_kernel<<<ewGrid, blk, 0, stream>>>(part, uk, uk);          // uk2
  pooldot_kernel<<<pdGrid, blk, 0, stream>>>(D2, story, uk, p_ptr_out); // p_ptr (D2 hot)

  // ---------------- vocab projection (split-K x2 + reduce)
  pvocab_kernel<<<VV / 64 * 2, blk, 0, stream>>>(hc, W1, partc);
  pvreduce_kernel<<<dim3(125, 32), blk, 0, stream>>>(partc, W1b, p_vocab_out);
}